// Round 3
// baseline (7005.778 us; speedup 1.0000x reference)
//
#include <hip/hip_runtime.h>
#include <stdint.h>

typedef __attribute__((ext_vector_type(8))) short bf16x8;
typedef __attribute__((ext_vector_type(4))) float f32x4;
typedef unsigned short u16;
typedef unsigned int u32;

#define MTOK 2048
#define DMODEL 1024
#define NCELL 4096
#define DCELL 256
#define DFF 4096
#define NVOCAB 50257

static __device__ __forceinline__ u16 f2bf(float f) {
  u32 u = __builtin_bit_cast(u32, f);
  u = (u + 0x7FFFu + ((u >> 16) & 1u)) >> 16;
  return (u16)u;
}
static __device__ __forceinline__ u32 pk2(float a, float b) {
  return (u32)f2bf(a) | ((u32)f2bf(b) << 16);
}
static __device__ __forceinline__ float sigm(float x) { return 1.0f / (1.0f + __expf(-x)); }

static __device__ __forceinline__ float blockReduceSum(float v) {
#pragma unroll
  for (int o = 32; o > 0; o >>= 1) v += __shfl_xor(v, o);
  __shared__ float sm[4];
  __syncthreads();
  if ((threadIdx.x & 63) == 0) sm[threadIdx.x >> 6] = v;
  __syncthreads();
  return sm[0] + sm[1] + sm[2] + sm[3];
}

// ---------------------------------------------------------------------------
// 128x128 GEMM (NT): C[2048,N] = A[2048,K](bf16) x B[N,K]^T
// grid.x = M-blocks (fast -> B-panel reuse), grid.y = N-blocks
// BF32: B fp32 (convert during staging). B row index clamped to N-1 always.
// EPI: 0 = Cf = alpha*acc (float4, ldc multiple of 4)
//      2 = coalesced scalar f32 stores, predicated col < Nstore (vocab, ragged ldc)
//      3 = fused SwiGLU (B cols interleaved even=g odd=u), bf16x8 stores
// Epilogue: LDS-staged per-mi chunk [32 rows][132 pad] f32, coalesced readback.
// ---------------------------------------------------------------------------
template<int BF32, int EPI>
__global__ __launch_bounds__(256, 4) void k_gemm(
    const u16* __restrict__ A, const void* __restrict__ Bv,
    float* __restrict__ Cf, u16* __restrict__ Cb,
    int N, int K, int lda, int ldb, int ldc, int Nstore, float alpha)
{
  __shared__ __align__(16) char smem[32768];
  u16* As = (u16*)smem;                 // 128*64 u16 = 16 KB
  u16* Bs = (u16*)(smem + 16384);       // 128*64 u16 = 16 KB
  float* eps = (float*)smem;            // epilogue: 32*132*4 = 16.9 KB (aliases As/Bs)

  const int tid = threadIdx.x;
  const int m0 = blockIdx.x * 128;
  const int n0 = blockIdx.y * 128;
  const int l = tid & 63;
  const int wv = tid >> 6;
  const int wm = wv >> 1, wn = wv & 1;
  const int lr = l & 15, lg = l >> 4;

  const u16* Bb = (const u16*)Bv;
  const float* Bf = (const float*)Bv;

  uint4 aR[4];
  uint4 bR[4];
  float4 bF[8];
  f32x4 acc[4][4] = {};
  const int nk = K >> 6;

  auto loadA = [&](int k0) {
#pragma unroll
    for (int c = 0; c < 4; ++c) {
      int id = c * 256 + tid;
      int row = id >> 3, kc = (id & 7) << 3;
      aR[c] = *(const uint4*)&A[(size_t)(m0 + row) * lda + k0 + kc];
    }
  };
  auto loadB = [&](int k0) {
    if constexpr (BF32) {
#pragma unroll
      for (int c = 0; c < 8; ++c) {
        int id = c * 256 + tid;
        int row = id >> 4, kc = (id & 15) << 2;
        int gr = n0 + row; if (gr > N - 1) gr = N - 1;
        bF[c] = *(const float4*)&Bf[(size_t)gr * ldb + k0 + kc];
      }
    } else {
#pragma unroll
      for (int c = 0; c < 4; ++c) {
        int id = c * 256 + tid;
        int row = id >> 3, kc = (id & 7) << 3;
        int gr = n0 + row; if (gr > N - 1) gr = N - 1;
        bR[c] = *(const uint4*)&Bb[(size_t)gr * ldb + k0 + kc];
      }
    }
  };
  auto stage = [&]() {
#pragma unroll
    for (int c = 0; c < 4; ++c) {
      int id = c * 256 + tid;
      int row = id >> 3, kc = (id & 7) << 3;
      *(uint4*)&As[row * 64 + kc] = aR[c];
    }
    if constexpr (BF32) {
#pragma unroll
      for (int c = 0; c < 8; ++c) {
        int id = c * 256 + tid;
        int row = id >> 4, kc = (id & 15) << 2;
        *(uint2*)&Bs[row * 64 + kc] = make_uint2(pk2(bF[c].x, bF[c].y), pk2(bF[c].z, bF[c].w));
      }
    } else {
#pragma unroll
      for (int c = 0; c < 4; ++c) {
        int id = c * 256 + tid;
        int row = id >> 3, kc = (id & 7) << 3;
        *(uint4*)&Bs[row * 64 + kc] = bR[c];
      }
    }
  };

  loadA(0); loadB(0);
  for (int s = 0; s < nk; ++s) {
    __syncthreads();
    stage();
    __syncthreads();
    if (s + 1 < nk) { loadA((s + 1) << 6); loadB((s + 1) << 6); }
#pragma unroll
    for (int kk = 0; kk < 2; ++kk) {
      bf16x8 fa[4], fb[4];
#pragma unroll
      for (int mi = 0; mi < 4; ++mi)
        fa[mi] = *(const bf16x8*)&As[(wm * 64 + mi * 16 + lr) * 64 + kk * 32 + lg * 8];
#pragma unroll
      for (int ni = 0; ni < 4; ++ni)
        fb[ni] = *(const bf16x8*)&Bs[(wn * 64 + ni * 16 + lr) * 64 + kk * 32 + lg * 8];
#pragma unroll
      for (int mi = 0; mi < 4; ++mi)
#pragma unroll
        for (int ni = 0; ni < 4; ++ni)
          acc[mi][ni] = __builtin_amdgcn_mfma_f32_16x16x32_bf16(fa[mi], fb[ni], acc[mi][ni], 0, 0, 0);
    }
  }

  // ------------------- LDS-staged coalesced epilogue -------------------
#pragma unroll
  for (int mi = 0; mi < 4; ++mi) {
    __syncthreads();   // first iter: all waves done reading As/Bs
#pragma unroll
    for (int ni = 0; ni < 4; ++ni) {
      int lcol = wn * 64 + ni * 16 + lr;
#pragma unroll
      for (int j = 0; j < 4; ++j) {
        int lrow = wm * 16 + lg * 4 + j;
        eps[lrow * 132 + lcol] = acc[mi][ni][j];
      }
    }
    __syncthreads();
    if constexpr (EPI == 0) {
      int lrow = tid >> 3, c0 = (tid & 7) << 4;
      int grow = m0 + (lrow >> 4) * 64 + mi * 16 + (lrow & 15);
      const float4* rp = (const float4*)&eps[lrow * 132 + c0];
#pragma unroll
      for (int q = 0; q < 4; ++q) {
        float4 r = rp[q];
        r.x *= alpha; r.y *= alpha; r.z *= alpha; r.w *= alpha;
        *(float4*)&Cf[(size_t)grow * ldc + n0 + c0 + q * 4] = r;
      }
    } else if constexpr (EPI == 2) {
      // coalesced scalar stores for misaligned ldc (vocab)
#pragma unroll
      for (int p = 0; p < 16; ++p) {
        int lrow = p * 2 + (tid >> 7);
        int col = tid & 127;
        int grow = m0 + (lrow >> 4) * 64 + mi * 16 + (lrow & 15);
        float r = eps[lrow * 132 + col];
        if (n0 + col < Nstore) Cf[(size_t)grow * ldc + n0 + col] = r;
      }
    } else {  // EPI == 3: silu(g)*u, even lcol = g, odd = u
      int lrow = tid >> 3, c0 = (tid & 7) << 4;
      int grow = m0 + (lrow >> 4) * 64 + mi * 16 + (lrow & 15);
      const float* r = &eps[lrow * 132 + c0];
      u32 w[4];
#pragma unroll
      for (int q = 0; q < 4; ++q) {
        float g0 = r[q * 4 + 0], u0 = r[q * 4 + 1];
        float g1 = r[q * 4 + 2], u1 = r[q * 4 + 3];
        w[q] = pk2(g0 * sigm(g0) * u0, g1 * sigm(g1) * u1);
      }
      *(uint4*)&Cb[(size_t)grow * DFF + ((n0 + c0) >> 1)] = make_uint4(w[0], w[1], w[2], w[3]);
    }
  }
}

// ---------------------------------------------------------------------------
// 64x64 GEMM (NT), bf16 B. EPI: 0 = Cf = acc; 1 = residual r = Cf+acc,
// Cf = r, Cb = bf16(r).
// ---------------------------------------------------------------------------
template<int EPI>
__global__ __launch_bounds__(256, 3) void k_gemm64(
    const u16* __restrict__ A, const u16* __restrict__ B,
    float* __restrict__ Cf, u16* __restrict__ Cb,
    int K, int lda, int ldb, int ldc)
{
  __shared__ __align__(16) u16 As[64 * 64];
  __shared__ __align__(16) u16 Bs[64 * 64];
  const int tid = threadIdx.x;
  const int m0 = blockIdx.x * 64;
  const int n0 = blockIdx.y * 64;
  const int l = tid & 63;
  const int wv = tid >> 6;
  const int wm = wv >> 1, wn = wv & 1;
  const int lr = l & 15, lg = l >> 4;

  uint4 aR[2], bR[2];
  f32x4 acc[2][2] = {};
  const int nk = K >> 6;

  auto loadAB = [&](int k0) {
#pragma unroll
    for (int c = 0; c < 2; ++c) {
      int id = c * 256 + tid;
      int row = id >> 3, kc = (id & 7) << 3;
      aR[c] = *(const uint4*)&A[(size_t)(m0 + row) * lda + k0 + kc];
      bR[c] = *(const uint4*)&B[(size_t)(n0 + row) * ldb + k0 + kc];
    }
  };
  auto stage = [&]() {
#pragma unroll
    for (int c = 0; c < 2; ++c) {
      int id = c * 256 + tid;
      int row = id >> 3, kc = (id & 7) << 3;
      *(uint4*)&As[row * 64 + kc] = aR[c];
      *(uint4*)&Bs[row * 64 + kc] = bR[c];
    }
  };

  loadAB(0);
  for (int s = 0; s < nk; ++s) {
    __syncthreads();
    stage();
    __syncthreads();
    if (s + 1 < nk) loadAB((s + 1) << 6);
#pragma unroll
    for (int kk = 0; kk < 2; ++kk) {
      bf16x8 fa[2], fb[2];
#pragma unroll
      for (int mi = 0; mi < 2; ++mi)
        fa[mi] = *(const bf16x8*)&As[(wm * 32 + mi * 16 + lr) * 64 + kk * 32 + lg * 8];
#pragma unroll
      for (int ni = 0; ni < 2; ++ni)
        fb[ni] = *(const bf16x8*)&Bs[(wn * 32 + ni * 16 + lr) * 64 + kk * 32 + lg * 8];
#pragma unroll
      for (int mi = 0; mi < 2; ++mi)
#pragma unroll
        for (int ni = 0; ni < 2; ++ni)
          acc[mi][ni] = __builtin_amdgcn_mfma_f32_16x16x32_bf16(fa[mi], fb[ni], acc[mi][ni], 0, 0, 0);
    }
  }

#pragma unroll
  for (int mi = 0; mi < 2; ++mi)
#pragma unroll
    for (int ni = 0; ni < 2; ++ni) {
      int col = n0 + wn * 32 + ni * 16 + lr;
#pragma unroll
      for (int j = 0; j < 4; ++j) {
        int row = m0 + wm * 32 + mi * 16 + lg * 4 + j;
        size_t off = (size_t)row * ldc + col;
        float v = acc[mi][ni][j];
        if constexpr (EPI == 0) {
          Cf[off] = v;
        } else {
          float r = Cf[off] + v;
          Cf[off] = r;
          Cb[off] = f2bf(r);
        }
      }
    }
}

// ---------------------------------------------------------------------------
// Per-layer weight transpose+convert fp32 [R,C] -> bf16 [C,R] (Wg/Wu
// interleave into WguT: dst row = 2c / 2c+1)
// ---------------------------------------------------------------------------
__global__ void k_transpose_layer(
    const float* __restrict__ Wi, const float* __restrict__ Wo,
    const float* __restrict__ Wg, const float* __restrict__ Wu,
    const float* __restrict__ Wd,
    u16* __restrict__ WiT, u16* __restrict__ WoT,
    u16* __restrict__ WguT, u16* __restrict__ WdT)
{
  int bid = blockIdx.x;
  const float* src; u16* dst; int R, C, t0, mul, add;
  if (bid < 256)       { src = Wi; dst = WiT;  R = 1024; C = 256;  t0 = bid;        mul = 1; add = 0; }
  else if (bid < 512)  { src = Wo; dst = WoT;  R = 256;  C = 1024; t0 = bid - 256;  mul = 1; add = 0; }
  else if (bid < 4608) { src = Wg; dst = WguT; R = 1024; C = 4096; t0 = bid - 512;  mul = 2; add = 0; }
  else if (bid < 8704) { src = Wu; dst = WguT; R = 1024; C = 4096; t0 = bid - 4608; mul = 2; add = 1; }
  else                 { src = Wd; dst = WdT;  R = 4096; C = 1024; t0 = bid - 8704; mul = 1; add = 0; }
  int tC = C >> 5;
  int r0 = (t0 / tC) << 5, c0 = (t0 % tC) << 5;
  __shared__ float tile[32][33];
  int ty = threadIdx.x >> 3;
  int tx = (threadIdx.x & 7) << 2;
  float4 v = *(const float4*)&src[(size_t)(r0 + ty) * C + c0 + tx];
  tile[ty][tx] = v.x; tile[ty][tx + 1] = v.y; tile[ty][tx + 2] = v.z; tile[ty][tx + 3] = v.w;
  __syncthreads();
  float a = tile[tx][ty], b = tile[tx + 1][ty], c = tile[tx + 2][ty], d = tile[tx + 3][ty];
  *(uint2*)&dst[((size_t)(c0 + ty) * mul + add) * R + r0 + tx] = make_uint2(pk2(a, b), pk2(c, d));
}

// fp32 -> bf16 flat convert (n divisible by 8)
__global__ void k_f2bf(const float* __restrict__ src, u16* __restrict__ dst, int n8)
{
  int i = blockIdx.x * 256 + threadIdx.x;
  if (i >= n8) return;
  const float4* s = (const float4*)(src + (size_t)i * 8);
  float4 a = s[0], b = s[1];
  *(uint4*)(dst + (size_t)i * 8) =
      make_uint4(pk2(a.x, a.y), pk2(a.z, a.w), pk2(b.x, b.y), pk2(b.z, b.w));
}

__global__ void k_embed_norm(const int* __restrict__ tok, const float* __restrict__ emb,
                             const float* __restrict__ w, float* __restrict__ xf,
                             u16* __restrict__ xb)
{
  int row = blockIdx.x;
  int t = tok[row];
  float4 v = ((const float4*)(emb + (size_t)t * DMODEL))[threadIdx.x];
  float tot = blockReduceSum(v.x * v.x + v.y * v.y + v.z * v.z + v.w * v.w);
  float inv = rsqrtf(tot * (1.0f / DMODEL) + 1e-6f);
  int d0 = threadIdx.x << 2;
  float4 wv = *(const float4*)(w + d0);
  float4 o;
  o.x = v.x * inv * wv.x; o.y = v.y * inv * wv.y;
  o.z = v.z * inv * wv.z; o.w = v.w * inv * wv.w;
  *(float4*)(xf + (size_t)row * DMODEL + d0) = o;
  *(uint2*)(xb + (size_t)row * DMODEL + d0) = make_uint2(pk2(o.x, o.y), pk2(o.z, o.w));
}

__global__ __launch_bounds__(256) void k_topk(const float* __restrict__ scores,
                                              float* __restrict__ wout, int* __restrict__ iout)
{
  int row = blockIdx.x * 4 + (threadIdx.x >> 6);
  int l = threadIdx.x & 63;
  const float* s = scores + (size_t)row * NCELL;
  float v[8]; int ix[8];
#pragma unroll
  for (int i = 0; i < 8; ++i) { v[i] = -3.4e38f; ix[i] = 0x7fffffff; }
  for (int j = 0; j < 64; ++j) {
    float x = s[j * 64 + l];
    if (x > v[7]) {
      v[7] = x; ix[7] = j * 64 + l;
#pragma unroll
      for (int q = 7; q > 0; --q) {
        if (v[q] > v[q - 1]) {
          float tv = v[q]; v[q] = v[q - 1]; v[q - 1] = tv;
          int tt = ix[q]; ix[q] = ix[q - 1]; ix[q - 1] = tt;
        }
      }
    }
  }
  float ov[8]; int oi[8];
#pragma unroll
  for (int r = 0; r < 8; ++r) {
    float bv = v[0]; int bi = ix[0];
#pragma unroll
    for (int o = 32; o > 0; o >>= 1) {
      float tv = __shfl_xor(bv, o);
      int tb = __shfl_xor(bi, o);
      if (tv > bv || (tv == bv && tb < bi)) { bv = tv; bi = tb; }
    }
    ov[r] = bv; oi[r] = bi;
    if (bi == ix[0]) {
#pragma unroll
      for (int q = 0; q < 7; ++q) { v[q] = v[q + 1]; ix[q] = ix[q + 1]; }
      v[7] = -3.4e38f; ix[7] = 0x7fffffff;
    }
  }
  if (l == 0) {
    float m = ov[0], sum = 0.f, e[8];
#pragma unroll
    for (int r = 0; r < 8; ++r) { e[r] = __expf(ov[r] - m); sum += e[r]; }
    float inv = 1.0f / sum;
#pragma unroll
    for (int r = 0; r < 8; ++r) {
      wout[(size_t)row * 8 + r] = e[r] * inv;
      iout[(size_t)row * 8 + r] = oi[r];
    }
  }
}

__global__ void k_readout(const float* __restrict__ cells, const int* __restrict__ ti,
                          const float* __restrict__ tw, const float* __restrict__ xin,
                          u16* __restrict__ rb)
{
  int row = blockIdx.x, d = threadIdx.x;
  float acc = xin[(size_t)row * DCELL + d];
#pragma unroll
  for (int k = 0; k < 8; ++k) {
    int ci = ti[row * 8 + k];
    float wk = tw[row * 8 + k];
    acc += wk * cells[(size_t)ci * DCELL + d];
  }
  rb[(size_t)row * DCELL + d] = f2bf(acc);
}

// Chunked decay scan: pass A computes per-chunk end states E[b][c][d]
__global__ void k_scan_a(const float* __restrict__ x, float* __restrict__ E,
                         const float* __restrict__ sgw, const float* __restrict__ sgb,
                         const float* __restrict__ sdec)
{
  int tid = blockIdx.x * 256 + threadIdx.x;   // 32768 = 8b * 4c * 1024d
  int d = tid & 1023, bc = tid >> 10;
  int b = bc >> 2, c = bc & 3;
  float dec = sigm(sdec[0]);
  dec = fminf(fmaxf(dec, 0.01f), 0.99f);
  float gw = sgw[d], gb = sgb[d];
  size_t base = ((size_t)b * 256 + c * 64) * DMODEL + d;
  float h = 0.f;
  for (int t = 0; t < 64; ++t) {
    float xv = x[base + (size_t)t * DMODEL];
    h = h * dec + sigm(xv * gw + gb) * xv;
  }
  E[tid] = h;
}

// pass B: combine carries, write pre = x + cs*co + sc*h
__global__ void k_scan_b(const float* __restrict__ x, const float* __restrict__ co,
                         const float* __restrict__ E, float* __restrict__ pre,
                         const float* __restrict__ sgw, const float* __restrict__ sgb,
                         const float* __restrict__ ssc, const float* __restrict__ sdec,
                         const float* __restrict__ csc)
{
  int tid = blockIdx.x * 256 + threadIdx.x;
  int d = tid & 1023, bc = tid >> 10;
  int b = bc >> 2, c = bc & 3;
  float dec = sigm(sdec[0]);
  dec = fminf(fmaxf(dec, 0.01f), 0.99f);
  float d2 = dec * dec, d4 = d2 * d2, d8 = d4 * d4, d16 = d8 * d8, d32 = d16 * d16;
  float d64 = d32 * d32;
  float cs = csc[0];
  float gw = sgw[d], gb = sgb[d], sc = ssc[d];
  float h = 0.f;
  for (int cc = 0; cc < c; ++cc) h = h * d64 + E[((b << 2) + cc) * 1024 + d];
  size_t base = ((size_t)b * 256 + c * 64) * DMODEL + d;
  for (int t = 0; t < 64; ++t) {
    size_t o = base + (size_t)t * DMODEL;
    float xv = x[o];
    float g = sigm(xv * gw + gb);
    h = h * dec + g * xv;
    pre[o] = xv + cs * co[o] + h * sc;
  }
}

__global__ void k_norm2(const float* __restrict__ pre, const float* __restrict__ nw,
                        const float* __restrict__ fw, float* __restrict__ xf,
                        u16* __restrict__ h2b)
{
  int row = blockIdx.x;
  float4 v = ((const float4*)(pre + (size_t)row * DMODEL))[threadIdx.x];
  float tot = blockReduceSum(v.x * v.x + v.y * v.y + v.z * v.z + v.w * v.w);
  float inv = rsqrtf(tot * (1.0f / DMODEL) + 1e-6f);
  int d0 = threadIdx.x << 2;
  float4 wv = *(const float4*)(nw + d0);
  float4 x1;
  x1.x = v.x * inv * wv.x; x1.y = v.y * inv * wv.y;
  x1.z = v.z * inv * wv.z; x1.w = v.w * inv * wv.w;
  *(float4*)(xf + (size_t)row * DMODEL + d0) = x1;
  float tot2 = blockReduceSum(x1.x * x1.x + x1.y * x1.y + x1.z * x1.z + x1.w * x1.w);
  float inv2 = rsqrtf(tot2 * (1.0f / DMODEL) + 1e-6f);
  float4 fv = *(const float4*)(fw + d0);
  *(uint2*)(h2b + (size_t)row * DMODEL + d0) =
      make_uint2(pk2(x1.x * inv2 * fv.x, x1.y * inv2 * fv.y),
                 pk2(x1.z * inv2 * fv.z, x1.w * inv2 * fv.w));
}

__global__ void k_norm_bf(const float* __restrict__ in, const float* __restrict__ w,
                          u16* __restrict__ ob)
{
  int row = blockIdx.x;
  float4 v = ((const float4*)(in + (size_t)row * DMODEL))[threadIdx.x];
  float tot = blockReduceSum(v.x * v.x + v.y * v.y + v.z * v.z + v.w * v.w);
  float inv = rsqrtf(tot * (1.0f / DMODEL) + 1e-6f);
  int d0 = threadIdx.x << 2;
  float4 wv = *(const float4*)(w + d0);
  *(uint2*)(ob + (size_t)row * DMODEL + d0) =
      make_uint2(pk2(v.x * inv * wv.x, v.y * inv * wv.y),
                 pk2(v.z * inv * wv.z, v.w * inv * wv.w));
}

// ---------------------------------------------------------------------------
extern "C" void kernel_launch(void* const* d_in, const int* in_sizes, int n_in,
                              void* d_out, int out_size, void* d_ws, size_t ws_size,
                              hipStream_t stream)
{
  const int*   tokens  = (const int*)d_in[0];
  const float* embed   = (const float*)d_in[1];
  const float* ln_in_w = (const float*)d_in[2];
  const float* ln_out_w= (const float*)d_in[3];
  const float* W_route = (const float*)d_in[4];
  const float* cells   = (const float*)d_in[5];
  const float* W_in    = (const float*)d_in[6];
  const float* W_out   = (const float*)d_in[7];
  const float* sdec    = (const float*)d_in[8];
  const float* sgw     = (const float*)d_in[9];
  const float* sgb     = (const float*)d_in[10];
  const float* ssc     = (const float*)d_in[11];
  const float* csc     = (const float*)d_in[12];
  const float* Wg      = (const float*)d_in[13];
  const float* Wu      = (const float*)d_in[14];
  const float* Wd      = (const float*)d_in[15];
  const float* ffw     = (const float*)d_in[16];
  const float* nrw     = (const float*)d_in[17];
  float* out = (float*)d_out;
  (void)in_sizes; (void)n_in; (void)out_size; (void)ws_size;

  char* ws = (char*)d_ws;
  size_t off = 0;
  auto alloc = [&](size_t bytes) -> void* {
    void* p = ws + off;
    off += (bytes + 255) & ~(size_t)255;
    return p;
  };

  // ---- epoch 1 (layer loop scratch) ----
  float* scores = (float*)alloc((size_t)MTOK * NCELL * 4);
  u16*  act_bf  = (u16*)alloc((size_t)MTOK * DFF * 2);      // aliased with s_pre
  float* s_pre  = (float*)act_bf;
  float* x_f    = (float*)alloc((size_t)MTOK * DMODEL * 4);
  u16*  x_bf    = (u16*)alloc((size_t)MTOK * DMODEL * 2);
  u16*  h2_bf   = (u16*)alloc((size_t)MTOK * DMODEL * 2);
  float* tw     = (float*)alloc((size_t)MTOK * 8 * 4);
  int*  ti      = (int*)alloc((size_t)MTOK * 8 * 4);
  float* xin    = (float*)alloc((size_t)MTOK * DCELL * 4);
  u16*  r_bf    = (u16*)alloc((size_t)MTOK * DCELL * 2);
  float* cellout= (float*)alloc((size_t)MTOK * DMODEL * 4);
  u16*  WiT     = (u16*)alloc((size_t)DCELL * DMODEL * 2);
  u16*  WoT     = (u16*)alloc((size_t)DMODEL * DCELL * 2);
  u16*  WguT    = (u16*)alloc((size_t)8192 * DMODEL * 2);
  u16*  WdT     = (u16*)alloc((size_t)DMODEL * DFF * 2);
  float* E      = (float*)alloc((size_t)32768 * 4);
  // ---- persistent tail (must be above embed_bf's 103 MB span) ----
  if (off < ((size_t)108 << 20)) off = (size_t)108 << 20;
  u16*  xf_bf   = (u16*)alloc((size_t)MTOK * DMODEL * 2);
  // ---- epoch 2 overlay (written after layer loop only) ----
  u16*  embed_bf = (u16*)ws;   // 50257*1024*2 = 102.9 MB, overlays dead epoch-1

  k_embed_norm<<<MTOK, 256, 0, stream>>>(tokens, embed, ln_in_w, x_f, x_bf);

  for (int lay = 0; lay < 8; ++lay) {
    const float* Wi_l = W_in  + (size_t)lay * DMODEL * DCELL;
    const float* Wo_l = W_out + (size_t)lay * DCELL * DMODEL;
    const float* Wg_l = Wg    + (size_t)lay * DMODEL * DFF;
    const float* Wu_l = Wu    + (size_t)lay * DMODEL * DFF;
    const float* Wd_l = Wd    + (size_t)lay * DFF * DMODEL;
    const float* Wr_l = W_route + (size_t)lay * NCELL * DMODEL;
    const float* cells_l = cells + (size_t)lay * NCELL * DCELL;

    k_transpose_layer<<<12800, 256, 0, stream>>>(Wi_l, Wo_l, Wg_l, Wu_l, Wd_l,
                                                 WiT, WoT, WguT, WdT);
    // scores = x @ Wr^T / 32
    k_gemm<1, 0><<<dim3(16, 32), 256, 0, stream>>>(x_bf, Wr_l, scores, nullptr,
        NCELL, DMODEL, DMODEL, DMODEL, NCELL, NCELL, 0.03125f);
    k_topk<<<512, 256, 0, stream>>>(scores, tw, ti);
    // x_in = x @ W_in
    k_gemm64<0><<<dim3(32, 4), 256, 0, stream>>>(x_bf, WiT, xin, nullptr,
        DMODEL, DMODEL, DMODEL, DCELL);
    k_readout<<<MTOK, 256, 0, stream>>>(cells_l, ti, tw, xin, r_bf);
    // cell_out = (readout + x_in) @ W_out
    k_gemm64<0><<<dim3(32, 16), 256, 0, stream>>>(r_bf, WoT, cellout, nullptr,
        DCELL, DCELL, DCELL, DMODEL);
    k_scan_a<<<128, 256, 0, stream>>>(x_f, E, sgw + lay * DMODEL,
        sgb + lay * DMODEL, sdec + lay);
    k_scan_b<<<128, 256, 0, stream>>>(x_f, cellout, E, s_pre, sgw + lay * DMODEL,
        sgb + lay * DMODEL, ssc + lay * DMODEL, sdec + lay, csc + lay);
    k_norm2<<<MTOK, 256, 0, stream>>>(s_pre, nrw + lay * DMODEL, ffw + lay * DMODEL,
        x_f, h2_bf);
    // act = silu(g)*u fused in epilogue (interleaved WguT)
    k_gemm<0, 3><<<dim3(16, 64), 256, 0, stream>>>(h2_bf, WguT, nullptr, act_bf,
        8192, DMODEL, DMODEL, DMODEL, 8192, 8192, 1.0f);
    // x = x + act @ Wd
    k_gemm64<1><<<dim3(32, 16), 256, 0, stream>>>(act_bf, WdT, x_f, x_bf,
        DFF, DFF, DFF, DMODEL);
  }

  k_norm_bf<<<MTOK, 256, 0, stream>>>(x_f, ln_out_w, xf_bf);
  // embed -> bf16 (overlays dead layer scratch)
  k_f2bf<<<(NVOCAB * (DMODEL / 8) + 255) / 256, 256, 0, stream>>>(
      embed, embed_bf, NVOCAB * (DMODEL / 8));
  // logits = xf @ embed_bf^T  (bf16 B, clamped loads, coalesced predicated stores)
  k_gemm<0, 2><<<dim3(16, 393), 256, 0, stream>>>(xf_bf, embed_bf, out, nullptr,
      NVOCAB, DMODEL, DMODEL, DMODEL, NVOCAB, NVOCAB, 1.0f);
}

// Round 4
// 5481.724 us; speedup vs baseline: 1.2780x; 1.2780x over previous
//
#include <hip/hip_runtime.h>
#include <stdint.h>

typedef __attribute__((ext_vector_type(8))) short bf16x8;
typedef __attribute__((ext_vector_type(4))) float f32x4;
typedef unsigned short u16;
typedef unsigned int u32;

#define MTOK 2048
#define DMODEL 1024
#define NCELL 4096
#define DCELL 256
#define DFF 4096
#define NVOCAB 50257

static __device__ __forceinline__ u16 f2bf(float f) {
  u32 u = __builtin_bit_cast(u32, f);
  u = (u + 0x7FFFu + ((u >> 16) & 1u)) >> 16;
  return (u16)u;
}
static __device__ __forceinline__ u32 pk2(float a, float b) {
  return (u32)f2bf(a) | ((u32)f2bf(b) << 16);
}
static __device__ __forceinline__ float sigm(float x) { return 1.0f / (1.0f + __expf(-x)); }

static __device__ __forceinline__ float blockReduceSum(float v) {
#pragma unroll
  for (int o = 32; o > 0; o >>= 1) v += __shfl_xor(v, o);
  __shared__ float sm[4];
  __syncthreads();
  if ((threadIdx.x & 63) == 0) sm[threadIdx.x >> 6] = v;
  __syncthreads();
  return sm[0] + sm[1] + sm[2] + sm[3];
}

// ---------------------------------------------------------------------------
// 128x128 GEMM (NT): C[2048,N] = A[2048,K](bf16) x B[N,K]^T
// 1D grid, XCD-affine swizzle: w = (bid%8)*(T/8) + bid/8; m-block = w%16
// (fast -> all 16 M-blocks of a panel on ONE XCD -> B panel fetched once).
// Grid size must be divisible by 8; M fixed at 2048 (16 M-blocks).
// BF32: B fp32 (convert during staging). B row index clamped to N-1.
// EPI: 0 = Cf = alpha*acc
//      2 = predicated f32 NONTEMPORAL stores col < Nstore (vocab)
//      3 = fused SwiGLU (B cols interleaved even=g odd=u) -> bf16 Cb
// ---------------------------------------------------------------------------
template<int BF32, int EPI>
__global__ __launch_bounds__(256, 2) void k_gemm(
    const u16* __restrict__ A, const void* __restrict__ Bv,
    float* __restrict__ Cf, u16* __restrict__ Cb,
    int N, int K, int lda, int ldb, int ldc, int Nstore, float alpha)
{
  __shared__ __align__(16) u16 As[128 * 64];
  __shared__ __align__(16) u16 Bs[128 * 64];
  const int tid = threadIdx.x;
  const int T = gridDim.x;
  const int bid = blockIdx.x;
  const int w = (bid & 7) * (T >> 3) + (bid >> 3);
  const int m0 = (w & 15) * 128;
  const int n0 = (w >> 4) * 128;
  const int l = tid & 63;
  const int wv = tid >> 6;
  const int wm = wv >> 1, wn = wv & 1;
  const int lr = l & 15, lg = l >> 4;

  const u16* Bb = (const u16*)Bv;
  const float* Bf = (const float*)Bv;

  uint4 aR[4];
  uint4 bR[4];
  float4 bF[8];
  f32x4 acc[4][4] = {};
  const int nk = K >> 6;

  auto loadA = [&](int k0) {
#pragma unroll
    for (int c = 0; c < 4; ++c) {
      int id = c * 256 + tid;
      int row = id >> 3, kc = (id & 7) << 3;
      aR[c] = *(const uint4*)&A[(size_t)(m0 + row) * lda + k0 + kc];
    }
  };
  auto loadB = [&](int k0) {
    if constexpr (BF32) {
#pragma unroll
      for (int c = 0; c < 8; ++c) {
        int id = c * 256 + tid;
        int row = id >> 4, kc = (id & 15) << 2;
        int gr = n0 + row; if (gr > N - 1) gr = N - 1;
        bF[c] = *(const float4*)&Bf[(size_t)gr * ldb + k0 + kc];
      }
    } else {
#pragma unroll
      for (int c = 0; c < 4; ++c) {
        int id = c * 256 + tid;
        int row = id >> 3, kc = (id & 7) << 3;
        int gr = n0 + row; if (gr > N - 1) gr = N - 1;
        bR[c] = *(const uint4*)&Bb[(size_t)gr * ldb + k0 + kc];
      }
    }
  };
  auto stage = [&]() {
#pragma unroll
    for (int c = 0; c < 4; ++c) {
      int id = c * 256 + tid;
      int row = id >> 3, kc = (id & 7) << 3;
      *(uint4*)&As[row * 64 + kc] = aR[c];
    }
    if constexpr (BF32) {
#pragma unroll
      for (int c = 0; c < 8; ++c) {
        int id = c * 256 + tid;
        int row = id >> 4, kc = (id & 15) << 2;
        *(uint2*)&Bs[row * 64 + kc] = make_uint2(pk2(bF[c].x, bF[c].y), pk2(bF[c].z, bF[c].w));
      }
    } else {
#pragma unroll
      for (int c = 0; c < 4; ++c) {
        int id = c * 256 + tid;
        int row = id >> 3, kc = (id & 7) << 3;
        *(uint4*)&Bs[row * 64 + kc] = bR[c];
      }
    }
  };

  loadA(0); loadB(0);
  for (int s = 0; s < nk; ++s) {
    __syncthreads();
    stage();
    __syncthreads();
    if (s + 1 < nk) { loadA((s + 1) << 6); loadB((s + 1) << 6); }
#pragma unroll
    for (int kk = 0; kk < 2; ++kk) {
      bf16x8 fa[4], fb[4];
#pragma unroll
      for (int mi = 0; mi < 4; ++mi)
        fa[mi] = *(const bf16x8*)&As[(wm * 64 + mi * 16 + lr) * 64 + kk * 32 + lg * 8];
#pragma unroll
      for (int ni = 0; ni < 4; ++ni)
        fb[ni] = *(const bf16x8*)&Bs[(wn * 64 + ni * 16 + lr) * 64 + kk * 32 + lg * 8];
#pragma unroll
      for (int mi = 0; mi < 4; ++mi)
#pragma unroll
        for (int ni = 0; ni < 4; ++ni)
          acc[mi][ni] = __builtin_amdgcn_mfma_f32_16x16x32_bf16(fa[mi], fb[ni], acc[mi][ni], 0, 0, 0);
    }
  }

#pragma unroll
  for (int mi = 0; mi < 4; ++mi)
#pragma unroll
    for (int ni = 0; ni < 4; ++ni) {
      int col = n0 + wn * 64 + ni * 16 + lr;
#pragma unroll
      for (int j = 0; j < 4; ++j) {
        int row = m0 + wm * 64 + mi * 16 + lg * 4 + j;
        float v = acc[mi][ni][j];
        if constexpr (EPI == 0) {
          Cf[(size_t)row * ldc + col] = v * alpha;
        } else if constexpr (EPI == 2) {
          if (col < Nstore)
            __builtin_nontemporal_store(v, &Cf[(size_t)row * ldc + col]);
        } else {  // EPI == 3: even col = g, odd col = u
          float p = __shfl_xor(v, 1);
          float a = v * sigm(v) * p;
          if ((lr & 1) == 0) Cb[(size_t)row * DFF + (col >> 1)] = f2bf(a);
        }
      }
    }
}

// ---------------------------------------------------------------------------
// 64x64 GEMM (NT), bf16 B. EPI: 0 = Cf = acc; 1 = residual r = Cf+acc,
// Cf = r, Cb = bf16(r).
// ---------------------------------------------------------------------------
template<int EPI>
__global__ __launch_bounds__(256, 3) void k_gemm64(
    const u16* __restrict__ A, const u16* __restrict__ B,
    float* __restrict__ Cf, u16* __restrict__ Cb,
    int K, int lda, int ldb, int ldc)
{
  __shared__ __align__(16) u16 As[64 * 64];
  __shared__ __align__(16) u16 Bs[64 * 64];
  const int tid = threadIdx.x;
  const int m0 = blockIdx.x * 64;
  const int n0 = blockIdx.y * 64;
  const int l = tid & 63;
  const int wv = tid >> 6;
  const int wm = wv >> 1, wn = wv & 1;
  const int lr = l & 15, lg = l >> 4;

  uint4 aR[2], bR[2];
  f32x4 acc[2][2] = {};
  const int nk = K >> 6;

  auto loadAB = [&](int k0) {
#pragma unroll
    for (int c = 0; c < 2; ++c) {
      int id = c * 256 + tid;
      int row = id >> 3, kc = (id & 7) << 3;
      aR[c] = *(const uint4*)&A[(size_t)(m0 + row) * lda + k0 + kc];
      bR[c] = *(const uint4*)&B[(size_t)(n0 + row) * ldb + k0 + kc];
    }
  };
  auto stage = [&]() {
#pragma unroll
    for (int c = 0; c < 2; ++c) {
      int id = c * 256 + tid;
      int row = id >> 3, kc = (id & 7) << 3;
      *(uint4*)&As[row * 64 + kc] = aR[c];
      *(uint4*)&Bs[row * 64 + kc] = bR[c];
    }
  };

  loadAB(0);
  for (int s = 0; s < nk; ++s) {
    __syncthreads();
    stage();
    __syncthreads();
    if (s + 1 < nk) loadAB((s + 1) << 6);
#pragma unroll
    for (int kk = 0; kk < 2; ++kk) {
      bf16x8 fa[2], fb[2];
#pragma unroll
      for (int mi = 0; mi < 2; ++mi)
        fa[mi] = *(const bf16x8*)&As[(wm * 32 + mi * 16 + lr) * 64 + kk * 32 + lg * 8];
#pragma unroll
      for (int ni = 0; ni < 2; ++ni)
        fb[ni] = *(const bf16x8*)&Bs[(wn * 32 + ni * 16 + lr) * 64 + kk * 32 + lg * 8];
#pragma unroll
      for (int mi = 0; mi < 2; ++mi)
#pragma unroll
        for (int ni = 0; ni < 2; ++ni)
          acc[mi][ni] = __builtin_amdgcn_mfma_f32_16x16x32_bf16(fa[mi], fb[ni], acc[mi][ni], 0, 0, 0);
    }
  }

#pragma unroll
  for (int mi = 0; mi < 2; ++mi)
#pragma unroll
    for (int ni = 0; ni < 2; ++ni) {
      int col = n0 + wn * 32 + ni * 16 + lr;
#pragma unroll
      for (int j = 0; j < 4; ++j) {
        int row = m0 + wm * 32 + mi * 16 + lg * 4 + j;
        size_t off = (size_t)row * ldc + col;
        float v = acc[mi][ni][j];
        if constexpr (EPI == 0) {
          Cf[off] = v;
        } else {
          float r = Cf[off] + v;
          Cf[off] = r;
          Cb[off] = f2bf(r);
        }
      }
    }
}

// ---------------------------------------------------------------------------
// Per-layer weight transpose+convert fp32 [R,C] -> bf16 [C,R] (Wg/Wu
// interleave into WguT: dst row = 2c / 2c+1)
// ---------------------------------------------------------------------------
__global__ void k_transpose_layer(
    const float* __restrict__ Wi, const float* __restrict__ Wo,
    const float* __restrict__ Wg, const float* __restrict__ Wu,
    const float* __restrict__ Wd,
    u16* __restrict__ WiT, u16* __restrict__ WoT,
    u16* __restrict__ WguT, u16* __restrict__ WdT)
{
  int bid = blockIdx.x;
  const float* src; u16* dst; int R, C, t0, mul, add;
  if (bid < 256)       { src = Wi; dst = WiT;  R = 1024; C = 256;  t0 = bid;        mul = 1; add = 0; }
  else if (bid < 512)  { src = Wo; dst = WoT;  R = 256;  C = 1024; t0 = bid - 256;  mul = 1; add = 0; }
  else if (bid < 4608) { src = Wg; dst = WguT; R = 1024; C = 4096; t0 = bid - 512;  mul = 2; add = 0; }
  else if (bid < 8704) { src = Wu; dst = WguT; R = 1024; C = 4096; t0 = bid - 4608; mul = 2; add = 1; }
  else                 { src = Wd; dst = WdT;  R = 4096; C = 1024; t0 = bid - 8704; mul = 1; add = 0; }
  int tC = C >> 5;
  int r0 = (t0 / tC) << 5, c0 = (t0 % tC) << 5;
  __shared__ float tile[32][33];
  int ty = threadIdx.x >> 3;
  int tx = (threadIdx.x & 7) << 2;
  float4 v = *(const float4*)&src[(size_t)(r0 + ty) * C + c0 + tx];
  tile[ty][tx] = v.x; tile[ty][tx + 1] = v.y; tile[ty][tx + 2] = v.z; tile[ty][tx + 3] = v.w;
  __syncthreads();
  float a = tile[tx][ty], b = tile[tx + 1][ty], c = tile[tx + 2][ty], d = tile[tx + 3][ty];
  *(uint2*)&dst[((size_t)(c0 + ty) * mul + add) * R + r0 + tx] = make_uint2(pk2(a, b), pk2(c, d));
}

// fp32 -> bf16 flat convert (n8 = count of 8-element groups)
__global__ void k_f2bf(const float* __restrict__ src, u16* __restrict__ dst, int n8)
{
  int i = blockIdx.x * 256 + threadIdx.x;
  if (i >= n8) return;
  const float4* s = (const float4*)(src + (size_t)i * 8);
  float4 a = s[0], b = s[1];
  *(uint4*)(dst + (size_t)i * 8) =
      make_uint4(pk2(a.x, a.y), pk2(a.z, a.w), pk2(b.x, b.y), pk2(b.z, b.w));
}

__global__ void k_embed_norm(const int* __restrict__ tok, const float* __restrict__ emb,
                             const float* __restrict__ w, float* __restrict__ xf,
                             u16* __restrict__ xb)
{
  int row = blockIdx.x;
  int t = tok[row];
  float4 v = ((const float4*)(emb + (size_t)t * DMODEL))[threadIdx.x];
  float tot = blockReduceSum(v.x * v.x + v.y * v.y + v.z * v.z + v.w * v.w);
  float inv = rsqrtf(tot * (1.0f / DMODEL) + 1e-6f);
  int d0 = threadIdx.x << 2;
  float4 wv = *(const float4*)(w + d0);
  float4 o;
  o.x = v.x * inv * wv.x; o.y = v.y * inv * wv.y;
  o.z = v.z * inv * wv.z; o.w = v.w * inv * wv.w;
  *(float4*)(xf + (size_t)row * DMODEL + d0) = o;
  *(uint2*)(xb + (size_t)row * DMODEL + d0) = make_uint2(pk2(o.x, o.y), pk2(o.z, o.w));
}

__global__ __launch_bounds__(256) void k_topk(const float* __restrict__ scores,
                                              float* __restrict__ wout, int* __restrict__ iout)
{
  int row = blockIdx.x * 4 + (threadIdx.x >> 6);
  int l = threadIdx.x & 63;
  const float* s = scores + (size_t)row * NCELL;
  float v[8]; int ix[8];
#pragma unroll
  for (int i = 0; i < 8; ++i) { v[i] = -3.4e38f; ix[i] = 0x7fffffff; }
  for (int j = 0; j < 64; ++j) {
    float x = s[j * 64 + l];
    if (x > v[7]) {
      v[7] = x; ix[7] = j * 64 + l;
#pragma unroll
      for (int q = 7; q > 0; --q) {
        if (v[q] > v[q - 1]) {
          float tv = v[q]; v[q] = v[q - 1]; v[q - 1] = tv;
          int tt = ix[q]; ix[q] = ix[q - 1]; ix[q - 1] = tt;
        }
      }
    }
  }
  float ov[8]; int oi[8];
#pragma unroll
  for (int r = 0; r < 8; ++r) {
    float bv = v[0]; int bi = ix[0];
#pragma unroll
    for (int o = 32; o > 0; o >>= 1) {
      float tv = __shfl_xor(bv, o);
      int tb = __shfl_xor(bi, o);
      if (tv > bv || (tv == bv && tb < bi)) { bv = tv; bi = tb; }
    }
    ov[r] = bv; oi[r] = bi;
    if (bi == ix[0]) {
#pragma unroll
      for (int q = 0; q < 7; ++q) { v[q] = v[q + 1]; ix[q] = ix[q + 1]; }
      v[7] = -3.4e38f; ix[7] = 0x7fffffff;
    }
  }
  if (l == 0) {
    float m = ov[0], sum = 0.f, e[8];
#pragma unroll
    for (int r = 0; r < 8; ++r) { e[r] = __expf(ov[r] - m); sum += e[r]; }
    float inv = 1.0f / sum;
#pragma unroll
    for (int r = 0; r < 8; ++r) {
      wout[(size_t)row * 8 + r] = e[r] * inv;
      iout[(size_t)row * 8 + r] = oi[r];
    }
  }
}

__global__ void k_readout(const float* __restrict__ cells, const int* __restrict__ ti,
                          const float* __restrict__ tw, const float* __restrict__ xin,
                          u16* __restrict__ rb)
{
  int row = blockIdx.x, d = threadIdx.x;
  float acc = xin[(size_t)row * DCELL + d];
#pragma unroll
  for (int k = 0; k < 8; ++k) {
    int ci = ti[row * 8 + k];
    float wk = tw[row * 8 + k];
    acc += wk * cells[(size_t)ci * DCELL + d];
  }
  rb[(size_t)row * DCELL + d] = f2bf(acc);
}

// Chunked decay scan: pass A computes per-chunk end states E[b][c][d]
__global__ void k_scan_a(const float* __restrict__ x, float* __restrict__ E,
                         const float* __restrict__ sgw, const float* __restrict__ sgb,
                         const float* __restrict__ sdec)
{
  int tid = blockIdx.x * 256 + threadIdx.x;   // 32768 = 8b * 4c * 1024d
  int d = tid & 1023, bc = tid >> 10;
  int b = bc >> 2, c = bc & 3;
  float dec = sigm(sdec[0]);
  dec = fminf(fmaxf(dec, 0.01f), 0.99f);
  float gw = sgw[d], gb = sgb[d];
  size_t base = ((size_t)b * 256 + c * 64) * DMODEL + d;
  float h = 0.f;
  for (int t = 0; t < 64; ++t) {
    float xv = x[base + (size_t)t * DMODEL];
    h = h * dec + sigm(xv * gw + gb) * xv;
  }
  E[tid] = h;
}

// pass B: combine carries, write pre = x + cs*co + sc*h
__global__ void k_scan_b(const float* __restrict__ x, const float* __restrict__ co,
                         const float* __restrict__ E, float* __restrict__ pre,
                         const float* __restrict__ sgw, const float* __restrict__ sgb,
                         const float* __restrict__ ssc, const float* __restrict__ sdec,
                         const float* __restrict__ csc)
{
  int tid = blockIdx.x * 256 + threadIdx.x;
  int d = tid & 1023, bc = tid >> 10;
  int b = bc >> 2, c = bc & 3;
  float dec = sigm(sdec[0]);
  dec = fminf(fmaxf(dec, 0.01f), 0.99f);
  float d2 = dec * dec, d4 = d2 * d2, d8 = d4 * d4, d16 = d8 * d8, d32 = d16 * d16;
  float d64 = d32 * d32;
  float cs = csc[0];
  float gw = sgw[d], gb = sgb[d], sc = ssc[d];
  float h = 0.f;
  for (int cc = 0; cc < c; ++cc) h = h * d64 + E[((b << 2) + cc) * 1024 + d];
  size_t base = ((size_t)b * 256 + c * 64) * DMODEL + d;
  for (int t = 0; t < 64; ++t) {
    size_t o = base + (size_t)t * DMODEL;
    float xv = x[o];
    float g = sigm(xv * gw + gb);
    h = h * dec + g * xv;
    pre[o] = xv + cs * co[o] + h * sc;
  }
}

__global__ void k_norm2(const float* __restrict__ pre, const float* __restrict__ nw,
                        const float* __restrict__ fw, float* __restrict__ xf,
                        u16* __restrict__ h2b)
{
  int row = blockIdx.x;
  float4 v = ((const float4*)(pre + (size_t)row * DMODEL))[threadIdx.x];
  float tot = blockReduceSum(v.x * v.x + v.y * v.y + v.z * v.z + v.w * v.w);
  float inv = rsqrtf(tot * (1.0f / DMODEL) + 1e-6f);
  int d0 = threadIdx.x << 2;
  float4 wv = *(const float4*)(nw + d0);
  float4 x1;
  x1.x = v.x * inv * wv.x; x1.y = v.y * inv * wv.y;
  x1.z = v.z * inv * wv.z; x1.w = v.w * inv * wv.w;
  *(float4*)(xf + (size_t)row * DMODEL + d0) = x1;
  float tot2 = blockReduceSum(x1.x * x1.x + x1.y * x1.y + x1.z * x1.z + x1.w * x1.w);
  float inv2 = rsqrtf(tot2 * (1.0f / DMODEL) + 1e-6f);
  float4 fv = *(const float4*)(fw + d0);
  *(uint2*)(h2b + (size_t)row * DMODEL + d0) =
      make_uint2(pk2(x1.x * inv2 * fv.x, x1.y * inv2 * fv.y),
                 pk2(x1.z * inv2 * fv.z, x1.w * inv2 * fv.w));
}

__global__ void k_norm_bf(const float* __restrict__ in, const float* __restrict__ w,
                          u16* __restrict__ ob)
{
  int row = blockIdx.x;
  float4 v = ((const float4*)(in + (size_t)row * DMODEL))[threadIdx.x];
  float tot = blockReduceSum(v.x * v.x + v.y * v.y + v.z * v.z + v.w * v.w);
  float inv = rsqrtf(tot * (1.0f / DMODEL) + 1e-6f);
  int d0 = threadIdx.x << 2;
  float4 wv = *(const float4*)(w + d0);
  *(uint2*)(ob + (size_t)row * DMODEL + d0) =
      make_uint2(pk2(v.x * inv * wv.x, v.y * inv * wv.y),
                 pk2(v.z * inv * wv.z, v.w * inv * wv.w));
}

// ---------------------------------------------------------------------------
extern "C" void kernel_launch(void* const* d_in, const int* in_sizes, int n_in,
                              void* d_out, int out_size, void* d_ws, size_t ws_size,
                              hipStream_t stream)
{
  const int*   tokens  = (const int*)d_in[0];
  const float* embed   = (const float*)d_in[1];
  const float* ln_in_w = (const float*)d_in[2];
  const float* ln_out_w= (const float*)d_in[3];
  const float* W_route = (const float*)d_in[4];
  const float* cells   = (const float*)d_in[5];
  const float* W_in    = (const float*)d_in[6];
  const float* W_out   = (const float*)d_in[7];
  const float* sdec    = (const float*)d_in[8];
  const float* sgw     = (const float*)d_in[9];
  const float* sgb     = (const float*)d_in[10];
  const float* ssc     = (const float*)d_in[11];
  const float* csc     = (const float*)d_in[12];
  const float* Wg      = (const float*)d_in[13];
  const float* Wu      = (const float*)d_in[14];
  const float* Wd      = (const float*)d_in[15];
  const float* ffw     = (const float*)d_in[16];
  const float* nrw     = (const float*)d_in[17];
  float* out = (float*)d_out;
  (void)in_sizes; (void)n_in; (void)out_size; (void)ws_size;

  char* ws = (char*)d_ws;
  size_t off = 0;
  auto alloc = [&](size_t bytes) -> void* {
    void* p = ws + off;
    off += (bytes + 255) & ~(size_t)255;
    return p;
  };

  // ---- epoch 1 (layer loop scratch) ----
  float* scores = (float*)alloc((size_t)MTOK * NCELL * 4);
  u16*  act_bf  = (u16*)alloc((size_t)MTOK * DFF * 2);      // aliased with s_pre
  float* s_pre  = (float*)act_bf;
  float* x_f    = (float*)alloc((size_t)MTOK * DMODEL * 4);
  u16*  x_bf    = (u16*)alloc((size_t)MTOK * DMODEL * 2);
  u16*  h2_bf   = (u16*)alloc((size_t)MTOK * DMODEL * 2);
  float* tw     = (float*)alloc((size_t)MTOK * 8 * 4);
  int*  ti      = (int*)alloc((size_t)MTOK * 8 * 4);
  float* xin    = (float*)alloc((size_t)MTOK * DCELL * 4);
  u16*  r_bf    = (u16*)alloc((size_t)MTOK * DCELL * 2);
  float* cellout= (float*)alloc((size_t)MTOK * DMODEL * 4);
  u16*  WiT     = (u16*)alloc((size_t)DCELL * DMODEL * 2);
  u16*  WoT     = (u16*)alloc((size_t)DMODEL * DCELL * 2);
  u16*  WguT    = (u16*)alloc((size_t)8192 * DMODEL * 2);
  u16*  WdT     = (u16*)alloc((size_t)DMODEL * DFF * 2);
  float* E      = (float*)alloc((size_t)32768 * 4);
  // ---- persistent tail (above embed_bf's 103 MB span) ----
  if (off < ((size_t)108 << 20)) off = (size_t)108 << 20;
  u16*  xf_bf   = (u16*)alloc((size_t)MTOK * DMODEL * 2);
  // ---- epoch 2 overlay (written only after layer loop) ----
  u16*  embed_bf = (u16*)ws;   // 102.9 MB, overlays dead epoch-1 scratch

  k_embed_norm<<<MTOK, 256, 0, stream>>>(tokens, embed, ln_in_w, x_f, x_bf);

  for (int lay = 0; lay < 8; ++lay) {
    const float* Wi_l = W_in  + (size_t)lay * DMODEL * DCELL;
    const float* Wo_l = W_out + (size_t)lay * DCELL * DMODEL;
    const float* Wg_l = Wg    + (size_t)lay * DMODEL * DFF;
    const float* Wu_l = Wu    + (size_t)lay * DMODEL * DFF;
    const float* Wd_l = Wd    + (size_t)lay * DFF * DMODEL;
    const float* Wr_l = W_route + (size_t)lay * NCELL * DMODEL;
    const float* cells_l = cells + (size_t)lay * NCELL * DCELL;

    k_transpose_layer<<<12800, 256, 0, stream>>>(Wi_l, Wo_l, Wg_l, Wu_l, Wd_l,
                                                 WiT, WoT, WguT, WdT);
    // scores = x @ Wr^T / 32   (512 blocks = 16 Mblk x 32 panels, XCD-swizzled)
    k_gemm<1, 0><<<512, 256, 0, stream>>>(x_bf, Wr_l, scores, nullptr,
        NCELL, DMODEL, DMODEL, DMODEL, NCELL, NCELL, 0.03125f);
    k_topk<<<512, 256, 0, stream>>>(scores, tw, ti);
    // x_in = x @ W_in
    k_gemm64<0><<<dim3(32, 4), 256, 0, stream>>>(x_bf, WiT, xin, nullptr,
        DMODEL, DMODEL, DMODEL, DCELL);
    k_readout<<<MTOK, 256, 0, stream>>>(cells_l, ti, tw, xin, r_bf);
    // cell_out = (readout + x_in) @ W_out
    k_gemm64<0><<<dim3(32, 16), 256, 0, stream>>>(r_bf, WoT, cellout, nullptr,
        DCELL, DCELL, DCELL, DMODEL);
    k_scan_a<<<128, 256, 0, stream>>>(x_f, E, sgw + lay * DMODEL,
        sgb + lay * DMODEL, sdec + lay);
    k_scan_b<<<128, 256, 0, stream>>>(x_f, cellout, E, s_pre, sgw + lay * DMODEL,
        sgb + lay * DMODEL, ssc + lay * DMODEL, sdec + lay, csc + lay);
    k_norm2<<<MTOK, 256, 0, stream>>>(s_pre, nrw + lay * DMODEL, ffw + lay * DMODEL,
        x_f, h2_bf);
    // act = silu(g)*u fused in epilogue (1024 blocks = 16 x 64 panels, swizzled)
    k_gemm<0, 3><<<1024, 256, 0, stream>>>(h2_bf, WguT, nullptr, act_bf,
        8192, DMODEL, DMODEL, DMODEL, 8192, 8192, 1.0f);
    // x = x + act @ Wd
    k_gemm64<1><<<dim3(32, 16), 256, 0, stream>>>(act_bf, WdT, x_f, x_bf,
        DFF, DFF, DFF, DMODEL);
  }

  k_norm_bf<<<MTOK, 256, 0, stream>>>(x_f, ln_out_w, xf_bf);
  // embed -> bf16 (overlays dead layer scratch)
  k_f2bf<<<(NVOCAB * (DMODEL / 8) + 255) / 256, 256, 0, stream>>>(
      embed, embed_bf, NVOCAB * (DMODEL / 8));
  // logits = xf @ embed_bf^T  (6288 blocks = 16 x 393 panels, XCD-swizzled,
  // nontemporal predicated stores)
  k_gemm<0, 2><<<6288, 256, 0, stream>>>(xf_bf, embed_bf, out, nullptr,
      NVOCAB, DMODEL, DMODEL, DMODEL, NVOCAB, NVOCAB, 1.0f);
}